// Round 7
// baseline (337.789 us; speedup 1.0000x reference)
//
#include <hip/hip_runtime.h>

using u16 = unsigned short;
typedef __attribute__((ext_vector_type(8))) short short8;
typedef __attribute__((ext_vector_type(4))) float f32x4;

__device__ __forceinline__ u16 f2bf(float f) {
  unsigned int u = __float_as_uint(f);
  u = (u + 0x7FFFu + ((u >> 16) & 1u)) >> 16;   // RNE, fine for non-NaN
  return (u16)u;
}
__device__ __forceinline__ float bf2f(u16 v) {
  return __uint_as_float(((unsigned int)v) << 16);
}

// async global->LDS, 16B per lane. LDS dest is wave-uniform base + lane*16.
__device__ __forceinline__ void gload16(const void* g, void* l) {
  __builtin_amdgcn_global_load_lds((const __attribute__((address_space(1))) void*)g,
                                   (__attribute__((address_space(3))) void*)l, 16, 0, 0);
}

#define B_ 4
#define S_ 4096
#define D_ 1024
#define H_ 16
#define HD_ 64
#define M_ (B_*S_)    // 16384
#define N1_ (3*D_)    // 3072
#define NSPLIT_ 4     // kv s-splits (partial buffers, no atomics)

// workspace layout (bytes)
#define OFF_XB    0ull                                  // x bf16 [M][1024]
#define OFF_WQKVT (OFF_XB    + (size_t)M_*D_*2)         // Wqkv^T bf16 [3072][1024]
#define OFF_WOT   (OFF_WQKVT + (size_t)N1_*D_*2)        // Wo^T bf16 [1024][1024]
#define OFF_QBUF  (OFF_WOT   + (size_t)D_*D_*2)         // Q bf16 [M][1024] (elu+1; later scaled to Q~)
#define OFF_KT    (OFF_QBUF  + (size_t)M_*D_*2)         // Kt bf16 [64][64][4096]; later W~T bf16 [4][1024][1024] + Ksum
#define OFF_VT    (OFF_KT    + (size_t)M_*D_*2)         // Vt bf16 [64][64][4096]
#define OFF_KV    (OFF_VT    + (size_t)M_*D_*2)         // KV partials fp32 [NSPLIT][bh][64*64]
#define OFF_KSUM  (OFF_KV    + (size_t)NSPLIT_*64*4096*4) // Ksum partials fp32 [NSPLIT][bh][64]
#define WS_NEEDED (OFF_KSUM  + (size_t)NSPLIT_*64*64*4)
// aliases into the dead-after-kv Kt region:
#define OFF_WT    OFF_KT                                 // W~T bf16 [4][1024][1024] = 8 MB
#define OFF_KSG   (OFF_KT + (size_t)8*1024*1024)         // Ksum summed fp32 [64][64] = 16 KB

// ---------------- merged prep: x->bf16, Wqkv^T, Wo^T (block-range switch) ----------------
__global__ __launch_bounds__(256) void prep_kernel(const float* __restrict__ x, u16* __restrict__ xb,
                                                   const float* __restrict__ Wqkv, u16* __restrict__ wqkvt,
                                                   const float* __restrict__ Wo, u16* __restrict__ wot)
{
  __shared__ float tile[32][33];
  int bid = blockIdx.x, tid = threadIdx.x;
  if (bid < 16384) {
    int i = bid * 256 + tid;               // n4 = M_*D_/4 = 4194304 = 16384*256 exactly
    float4 v = ((const float4*)x)[i];
    uint2 o;
    o.x = (unsigned)f2bf(v.x) | ((unsigned)f2bf(v.y) << 16);
    o.y = (unsigned)f2bf(v.z) | ((unsigned)f2bf(v.w) << 16);
    ((uint2*)xb)[i] = o;
    return;
  }
  const float* in; u16* out; int R, C, cb, rb;
  if (bid < 19456) {
    int t = bid - 16384;  in = Wqkv; out = wqkvt; R = D_; C = N1_;
    cb = t % 96; rb = t / 96;
  } else {
    int t = bid - 19456;  in = Wo; out = wot; R = D_; C = D_;
    cb = t % 32; rb = t / 32;
  }
  int tx = tid & 31, ty = tid >> 5;
  int c0 = cb * 32, r0 = rb * 32;
#pragma unroll
  for (int i = 0; i < 4; i++)
    tile[ty + i*8][tx] = in[(size_t)(r0 + ty + i*8) * C + c0 + tx];
  __syncthreads();
#pragma unroll
  for (int i = 0; i < 4; i++)
    out[(size_t)(c0 + ty + i*8) * R + r0 + tx] = f2bf(tile[tx][ty + i*8]);
}

// ---------------- main GEMM: 256x256 tile, BK=32, ring-4 LDS pipeline ----------------
// C[M,N] = A[M,K](bf16) * Bt[N,K](bf16)^T.
// 512 threads = 8 waves (2 M x 4 N); wave tile 128x64; acc 8x4 frags.
// MODE is a TEMPLATE param (round-6 lesson: runtime mode select in the B-address
// chain + shared epilogue branching perturbed codegen -> qkv 114->146us, MfmaUtil
// 38->29. Compile-time if constexpr restores the r5-identical MODE=1 instruction
// stream). MODE 1: qkv epilogue (Q elu+1 / Kt,Vt transposed pack).
// MODE 2: fp32 store, per-batch B base (Bt += (bm>>12)<<20) -- batched W~ GEMM.
// REGISTER NOTE: acc[8][4] = 128 unified regs alone -> NEVER set min-waves > 2
// (round-4 lesson: launch_bounds(512,4) caps unified VGPR+AGPR at 128 -> spill, 13x slower).
// Ring-4 ledger: per K-step t, stage t+3 into slot (t+3)&3 (freed by barrier of t-1);
// end-of-step vmcnt(8) -> tile t+1 landed, t+2/t+3 in flight; drain tail 8/4/0.
// LDS per 16KB panel: paired rows [128 phys rows][8 chunks of 16B];
// logical (r,kchunk) at phys chunk pch = (((r&1)<<2)|kchunk) ^ ((r>>1)&7).
// XOR involution applied to the global fetch address on staging and to the ds_read
// address on fragment read -> conflict-free (verified: 0 bank conflicts).
template<int MODE>
__global__ __launch_bounds__(512, 2) void gemm256(
    const u16* __restrict__ A, const u16* __restrict__ Bt,
    float* __restrict__ Cf, u16* __restrict__ qout,
    u16* __restrict__ Kt, u16* __restrict__ Vt,
    int M, int N, int K)
{
  __shared__ __align__(16) char smem[131072];   // [4 slots][A 16KB] + [4 slots][B 16KB]
  int tid = threadIdx.x;
  int w = tid >> 6, lane = tid & 63;
  int quad = lane >> 4, l16 = lane & 15;
  int wm = w >> 2, wn = w & 3;

  // XCD-aware bijective swizzle (nwg % 8 == 0)
  int nwg = gridDim.x * gridDim.y;
  int flat = blockIdx.y * gridDim.x + blockIdx.x;
  int wg = (flat & 7) * (nwg >> 3) + (flat >> 3);
  int bx = wg % gridDim.x, by = wg / gridDim.x;
  int bm = by * 256, bn = bx * 256;

  const u16* Bp;
  if constexpr (MODE == 2) Bp = Bt + ((size_t)(bm >> 12) << 20);
  else                     Bp = Bt;

  // staging: lane covers LDS bytes lane*16 in its wave's 1KB strip; inverse swizzle
  // goes into the global source address (rule #21: linear dest + inverse-swz source).
  int prl = lane >> 3;                          // phys row-in-strip 0..7
  int c4  = (lane & 7) ^ prl;                   // logical chunk 0..7
  int r0  = ((w << 3) + prl) * 2 + (c4 >> 2);   // logical row 0..127
  int koff = (c4 & 3) * 8;                      // logical k element offset
  const u16* gA0 = A  + (size_t)(bm + r0) * K + koff;
  const u16* gB0 = Bp + (size_t)(bn + r0) * K + koff;
  size_t rowskip = (size_t)128 * K;             // logical rows +128 (phys rows +64)
  char* smemc = smem;
  int ldsAw = w * 1024;                         // wave-uniform LDS bases
  int ldsBw = 65536 + w * 1024;

  // fragment read bases: pr&7 = (l16>>1)&7 (mi*8, wm*64 vanish mod 8)
  int ph = (((l16 & 1) << 2) | quad) ^ ((l16 >> 1) & 7);
  int baseA = wm * 8192 + (l16 >> 1) * 128 + ph * 16;
  int baseB = 65536 + wn * 4096 + (l16 >> 1) * 128 + ph * 16;

  f32x4 acc[8][4];
#pragma unroll
  for (int i = 0; i < 8; i++)
#pragma unroll
    for (int j = 0; j < 4; j++) acc[i][j] = (f32x4)0.0f;

  int nt = K >> 5;   // K=1024 -> 32 steps

#define STG(tt, slot) {                                                   \
    const u16* a0_ = gA0 + (tt) * 32;                                     \
    const u16* b0_ = gB0 + (tt) * 32;                                     \
    gload16(a0_,           smemc + (slot)*16384 + ldsAw);                 \
    gload16(a0_ + rowskip, smemc + (slot)*16384 + 8192 + ldsAw);          \
    gload16(b0_,           smemc + (slot)*16384 + ldsBw);                 \
    gload16(b0_ + rowskip, smemc + (slot)*16384 + 8192 + ldsBw);          \
  }

#define COMPUTE(slot) {                                                              \
    const char* sb = smemc + (slot) * 16384;                                         \
    short8 bfr[4], af[8];                                                            \
    _Pragma("unroll")                                                                \
    for (int nj = 0; nj < 4; nj++) bfr[nj] = *(const short8*)(sb + baseB + nj*1024); \
    _Pragma("unroll")                                                                \
    for (int mi = 0; mi < 8; mi++) af[mi] = *(const short8*)(sb + baseA + mi*1024);  \
    __builtin_amdgcn_s_setprio(1);                                                   \
    _Pragma("unroll")                                                                \
    for (int mi = 0; mi < 8; mi++)                                                   \
      _Pragma("unroll")                                                              \
      for (int nj = 0; nj < 4; nj++)                                                 \
        acc[mi][nj] = __builtin_amdgcn_mfma_f32_16x16x32_bf16(af[mi], bfr[nj],       \
                                                              acc[mi][nj], 0, 0, 0); \
    __builtin_amdgcn_s_setprio(0);                                                   \
  }

#define WAITBAR(n) {                                                      \
    asm volatile("s_waitcnt vmcnt(" #n ")" ::: "memory");                 \
    __builtin_amdgcn_s_barrier();                                         \
    asm volatile("" ::: "memory");                                        \
  }

  // prologue: 3 tiles in flight; wait for tile 0 only
  STG(0, 0); STG(1, 1); STG(2, 2);
  WAITBAR(8)

  // main loop: steps 0 .. nt-5; STG(t+3) always valid (t+3 <= nt-2)
  for (int tb = 0; tb < nt - 4; tb += 4) {
#pragma unroll
    for (int i = 0; i < 4; ++i) {
      int t = tb + i;
      STG(t + 3, ((i + 3) & 3));        // slot (t-1)&3: freed by preceding barrier
      COMPUTE(i)
      WAITBAR(8)                        // t+2, t+3 stay in flight; t+1 landed
    }
  }

  // drain tail: steps nt-4 .. nt-1 in slots 0..3, wait counts shrink 8/4/0
  STG(nt - 1, 3);                       // slot 3 freed by last main-loop barrier
  COMPUTE(0)
  WAITBAR(8)                            // nt-3,nt-2,nt-1 outstanding(12) -> nt-3 landed
  COMPUTE(1)
  WAITBAR(4)                            // nt-2,nt-1 outstanding(8) -> nt-2 landed
  COMPUTE(2)
  WAITBAR(0)                            // nt-1 landed
  COMPUTE(3)

#undef STG
#undef COMPUTE
#undef WAITBAR

  // C/D layout: col = lane&15 (+nj*16), row = quad*4 + reg (verified m89/m91)
  int colbase = bn + wn * 64;
  if constexpr (MODE != 1) {
#pragma unroll
    for (int mi = 0; mi < 8; mi++) {
      int row0 = bm + wm * 128 + mi * 16 + quad * 4;
#pragma unroll
      for (int nj = 0; nj < 4; nj++) {
        int col = colbase + nj * 16 + l16;
#pragma unroll
        for (int r = 0; r < 4; r++)
          Cf[(size_t)(row0 + r) * N + col] = acc[mi][nj][r];
      }
    }
  } else {
    int cls = colbase >> 10;   // 0=Q, 1=K, 2=V (wave-uniform: 64 | 1024)
    if (cls == 0) {
#pragma unroll
      for (int mi = 0; mi < 8; mi++) {
        int row0 = bm + wm * 128 + mi * 16 + quad * 4;
#pragma unroll
        for (int nj = 0; nj < 4; nj++) {
          int col = colbase + nj * 16 + l16;
#pragma unroll
          for (int r = 0; r < 4; r++) {
            float v = acc[mi][nj][r];
            v = (v > 0.0f) ? (v + 1.0f) : __expf(v);   // elu+1
            qout[(size_t)(row0 + r) * D_ + col] = f2bf(v);
          }
        }
      }
    } else {
      int b = bm >> 12;                       // 4096 rows per batch; bm % 4096 block-uniform
      int h = (colbase & 1023) >> 6;          // head of this wave's 64-col subtile
      u16* dst = (cls == 1 ? Kt : Vt) + (size_t)((b * 16 + h) * 64) * 4096;
      int sb0 = (bm & 4095) + wm * 128;
      bool doElu = (cls == 1);
#pragma unroll
      for (int mi = 0; mi < 8; mi++) {
        int s = sb0 + mi * 16 + quad * 4;
#pragma unroll
        for (int nj = 0; nj < 4; nj++) {
          int d = nj * 16 + l16;
          float v0 = acc[mi][nj][0], v1 = acc[mi][nj][1], v2 = acc[mi][nj][2], v3 = acc[mi][nj][3];
          if (doElu) {
            v0 = (v0 > 0.0f) ? (v0 + 1.0f) : __expf(v0);
            v1 = (v1 > 0.0f) ? (v1 + 1.0f) : __expf(v1);
            v2 = (v2 > 0.0f) ? (v2 + 1.0f) : __expf(v2);
            v3 = (v3 > 0.0f) ? (v3 + 1.0f) : __expf(v3);
          }
          uint2 o;
          o.x = (unsigned)f2bf(v0) | ((unsigned)f2bf(v1) << 16);
          o.y = (unsigned)f2bf(v2) | ((unsigned)f2bf(v3) << 16);
          *(uint2*)(dst + (size_t)d * 4096 + s) = o;   // 4 consecutive s, one d
        }
      }
    }
  }
}

// ---------------- KV partial[p][bh] = sum_{s in split p} K[s,d]V[s,v]; NO global atomics ----------------
__global__ __launch_bounds__(256) void kv_kernel(const u16* __restrict__ Kt,
                                                 const u16* __restrict__ Vt,
                                                 float* __restrict__ KVp,
                                                 float* __restrict__ Ksp)
{
  __shared__ float red[4096];
  __shared__ float redS[64];
  int tid = threadIdx.x;
  int bh = blockIdx.x;
  int ssplit = blockIdx.y;
  int wave = tid >> 6, lane = tid & 63, quad = lane >> 4, l16 = lane & 15;
  int sbase = ssplit * (S_ / NSPLIT_) + wave * (S_ / NSPLIT_ / 4);
  const u16* Kb = Kt + (size_t)bh * 64 * 4096;
  const u16* Vb = Vt + (size_t)bh * 64 * 4096;
  short8 ones;
#pragma unroll
  for (int e = 0; e < 8; ++e) ones[e] = (short)0x3F80;   // bf16 1.0

  for (int i = tid; i < 4096; i += 256) red[i] = 0.0f;
  if (tid < 64) redS[tid] = 0.0f;

  f32x4 acc[4][4], accs[4];
#pragma unroll
  for (int i = 0; i < 4; i++) {
    accs[i] = (f32x4)0.0f;
#pragma unroll
    for (int j = 0; j < 4; j++) acc[i][j] = (f32x4)0.0f;
  }

  for (int kk = 0; kk < S_ / NSPLIT_ / 4 / 32; ++kk) {   // 8 iters of 32 s
    int s = sbase + kk * 32 + quad * 8;
    short8 af[4], bfr[4];
#pragma unroll
    for (int i = 0; i < 4; i++) {
      af[i]  = *(const short8*)(Kb + (size_t)(i*16 + l16) * 4096 + s);
      bfr[i] = *(const short8*)(Vb + (size_t)(i*16 + l16) * 4096 + s);
    }
#pragma unroll
    for (int i = 0; i < 4; i++) {
#pragma unroll
      for (int j = 0; j < 4; j++)
        acc[i][j] = __builtin_amdgcn_mfma_f32_16x16x32_bf16(af[i], bfr[j], acc[i][j], 0, 0, 0);
      accs[i] = __builtin_amdgcn_mfma_f32_16x16x32_bf16(af[i], ones, accs[i], 0, 0, 0);
    }
  }
  __syncthreads();   // zeroing complete
#pragma unroll
  for (int i = 0; i < 4; i++) {
    int d0 = i*16 + quad*4;
#pragma unroll
    for (int j = 0; j < 4; j++)
#pragma unroll
      for (int r = 0; r < 4; r++)
        atomicAdd(&red[(d0 + r) * 64 + j*16 + l16], acc[i][j][r]);   // LDS ds_add_f32
    if (l16 == 0)
#pragma unroll
      for (int r = 0; r < 4; r++)
        atomicAdd(&redS[d0 + r], accs[i][r]);
  }
  __syncthreads();
  float* dst = KVp + ((size_t)ssplit * 64 + bh) * 4096;
  for (int i = tid; i < 4096; i += 256) dst[i] = red[i];
  if (tid < 64) Ksp[((size_t)ssplit * 64 + bh) * 64 + tid] = redS[tid];
}

// ---------------- kvw: W~T[b][c][h*64+d] = sum_v KV_bh[d,v] * Wo[h*64+v, c] ----------------
// Algebra: out = sum_h diag(1/n_h) Q_h KV_h Wo_h = Q~ @ W~_b (per batch), where
// W~[h*64+d, c] = (KV_bh @ Wo_h)[d, c]. Sums the NSPLIT KVp partials, computes W~
// via MFMA (A = wot rows c, B = KV rows d -> D[row=c,col=d]), stores W~T[c][hd]
// (the Bt layout gemm256 wants). Also sums Ksp -> ksum fp32.
// Grid (8 c-tiles of 128, 64 bh); 256 thr = 4 waves, wave = 32 c-rows.
__global__ __launch_bounds__(256) void kvw_kernel(const float* __restrict__ KVp,
                                                  const float* __restrict__ Ksp,
                                                  const u16* __restrict__ wot,
                                                  u16* __restrict__ wt,
                                                  float* __restrict__ ksum)
{
  __shared__ u16 kvlds[4096];   // KV_bh [d][v] bf16
  int tid = threadIdx.x;
  int ct = blockIdx.x;          // c-tile 0..7
  int bh = blockIdx.y;          // 0..63
  int b = bh >> 4, h = bh & 15;
  const float* kvsrc = KVp + (size_t)bh * 4096;
  for (int i = tid; i < 4096; i += 256) {
    float s = kvsrc[i] + kvsrc[i + 64*4096] + kvsrc[i + 2*64*4096] + kvsrc[i + 3*64*4096];
    kvlds[i] = f2bf(s);
  }
  if (ct == 0 && tid < 64) {
    const float* ks = Ksp + (size_t)bh * 64;
    ksum[bh * 64 + tid] = ks[tid] + ks[tid + 64*64] + ks[tid + 2*64*64] + ks[tid + 3*64*64];
  }
  __syncthreads();
  int w = tid >> 6, lane = tid & 63, quad = lane >> 4, l16 = lane & 15;

  // B-frags: KV rows d = nj*16+l16, k-slice v = ks*32+quad*8 (hoisted, reused by both mi)
  short8 bfr[2][4];
#pragma unroll
  for (int ks = 0; ks < 2; ++ks)
#pragma unroll
    for (int nj = 0; nj < 4; ++nj)
      bfr[ks][nj] = *(const short8*)(&kvlds[(nj*16 + l16) * 64 + ks*32 + quad*8]);

  f32x4 acc[2][4];
#pragma unroll
  for (int i = 0; i < 2; i++)
#pragma unroll
    for (int j = 0; j < 4; j++) acc[i][j] = (f32x4)0.0f;

  int c0 = ct * 128 + w * 32;
#pragma unroll
  for (int ks = 0; ks < 2; ++ks) {
#pragma unroll
    for (int mi = 0; mi < 2; ++mi) {
      short8 af = *(const short8*)(wot + (size_t)(c0 + mi*16 + l16) * 1024 + h*64 + ks*32 + quad*8);
#pragma unroll
      for (int nj = 0; nj < 4; ++nj)
        acc[mi][nj] = __builtin_amdgcn_mfma_f32_16x16x32_bf16(af, bfr[ks][nj], acc[mi][nj], 0, 0, 0);
    }
  }
  // D layout: row = c-local (quad*4+r), col = d (nj*16+l16)
  u16* dst = wt + ((size_t)b << 20);
#pragma unroll
  for (int mi = 0; mi < 2; ++mi) {
    int c = c0 + mi*16 + quad*4;
#pragma unroll
    for (int nj = 0; nj < 4; ++nj) {
      int hd = h*64 + nj*16 + l16;
#pragma unroll
      for (int r = 0; r < 4; ++r)
        dst[(size_t)(c + r) * 1024 + hd] = f2bf(acc[mi][nj][r]);
    }
  }
}

// ---------------- qscale: qbuf[s, h*64+d] /= (sum_d' qbuf[s,h*64+d']*ksum_bh[d'] + eps) ----------------
// In-place row scaling; 4 waves = 4 rows per block. Lane ln covers elems ln*16..+16
// (one head per lane-group: h = ln>>2); 4-lane shfl_xor group-reduce gives n_h.
__global__ __launch_bounds__(256) void qscale_kernel(u16* __restrict__ qbuf,
                                                     const float* __restrict__ ksum)
{
  __shared__ float ks[1024];
  int tid = threadIdx.x;
  int blk = blockIdx.x;          // 4096 blocks
  int b = blk >> 10;             // 1024 blocks per batch
  for (int i = tid; i < 1024; i += 256) ks[i] = ksum[b * 1024 + i];
  __syncthreads();
  int wv = tid >> 6, ln = tid & 63;
  int s = blk * 4 + wv;
  u16* row = qbuf + (size_t)s * 1024 + ln * 16;
  short8 qa = *(const short8*)row;
  short8 qb = *(const short8*)(row + 8);
  int h4 = (ln >> 2) * 64 + (ln & 3) * 16;   // ksum base for this lane's 16 elems
  float p = 0.0f;
#pragma unroll
  for (int j = 0; j < 8; ++j) p += bf2f((u16)qa[j]) * ks[h4 + j];
#pragma unroll
  for (int j = 0; j < 8; ++j) p += bf2f((u16)qb[j]) * ks[h4 + 8 + j];
  p += __shfl_xor(p, 1);
  p += __shfl_xor(p, 2);                     // all 4 lanes of the head-group hold n_h
  float inv = 1.0f / (p + 1e-6f);
  short8 oa, ob;
#pragma unroll
  for (int j = 0; j < 8; ++j) {
    oa[j] = (short)f2bf(bf2f((u16)qa[j]) * inv);
    ob[j] = (short)f2bf(bf2f((u16)qb[j]) * inv);
  }
  *(short8*)row = oa;
  *(short8*)(row + 8) = ob;
}

extern "C" void kernel_launch(void* const* d_in, const int* in_sizes, int n_in,
                              void* d_out, int out_size, void* d_ws, size_t ws_size,
                              hipStream_t stream) {
  const float* x    = (const float*)d_in[0];
  const float* Wqkv = (const float*)d_in[1];
  const float* Wo   = (const float*)d_in[2];
  float* out = (float*)d_out;
  char* ws = (char*)d_ws;
  if (ws_size < WS_NEEDED) return;  // visible failure, no corruption

  u16*   xb    = (u16*)  (ws + OFF_XB);
  u16*   wqkvt = (u16*)  (ws + OFF_WQKVT);
  u16*   wot   = (u16*)  (ws + OFF_WOT);
  u16*   qbuf  = (u16*)  (ws + OFF_QBUF);
  u16*   kt    = (u16*)  (ws + OFF_KT);
  u16*   vt    = (u16*)  (ws + OFF_VT);
  float* kvp   = (float*)(ws + OFF_KV);
  float* ksp   = (float*)(ws + OFF_KSUM);
  u16*   wt    = (u16*)  (ws + OFF_WT);     // aliases Kt: dead after kv_kernel
  float* ksg   = (float*)(ws + OFF_KSG);    // aliases Kt + 8MB

  prep_kernel<<<20480, 256, 0, stream>>>(x, xb, Wqkv, wqkvt, Wo, wot);
  // qkv = x @ Wqkv; epilogue splits Q (elu, [M][1024]) / Kt,Vt (transposed [bh][d][S])
  gemm256<1><<<dim3(N1_/256, M_/256), 512, 0, stream>>>(xb, wqkvt, nullptr, qbuf, kt, vt,
                                                        M_, N1_, D_);
  kv_kernel<<<dim3(64, NSPLIT_), 256, 0, stream>>>(kt, vt, kvp, ksp);
  // W~T precompute (0.54 GF) + Ksum reduction
  kvw_kernel<<<dim3(8, 64), 256, 0, stream>>>(kvp, ksp, wot, wt, ksg);
  // Q~ = Q / (Q.Ksum + eps), in place
  qscale_kernel<<<4096, 256, 0, stream>>>(qbuf, ksg);
  // out = Q~ @ W~_b (batched B via compile-time MODE=2), fp32 out
  gemm256<2><<<dim3(D_/256, M_/256), 512, 0, stream>>>(qbuf, wt, out, nullptr, nullptr, nullptr,
                                                       M_, D_, D_);
}

// Round 8
// 293.196 us; speedup vs baseline: 1.1521x; 1.1521x over previous
//
#include <hip/hip_runtime.h>

using u16 = unsigned short;
typedef __attribute__((ext_vector_type(8))) short short8;
typedef __attribute__((ext_vector_type(4))) float f32x4;

__device__ __forceinline__ u16 f2bf(float f) {
  unsigned int u = __float_as_uint(f);
  u = (u + 0x7FFFu + ((u >> 16) & 1u)) >> 16;   // RNE, fine for non-NaN
  return (u16)u;
}
__device__ __forceinline__ float bf2f(u16 v) {
  return __uint_as_float(((unsigned int)v) << 16);
}

// async global->LDS, 16B per lane. LDS dest is wave-uniform base + lane*16.
__device__ __forceinline__ void gload16(const void* g, void* l) {
  __builtin_amdgcn_global_load_lds((const __attribute__((address_space(1))) void*)g,
                                   (__attribute__((address_space(3))) void*)l, 16, 0, 0);
}

#define B_ 4
#define S_ 4096
#define D_ 1024
#define H_ 16
#define HD_ 64
#define M_ (B_*S_)    // 16384
#define N1_ (3*D_)    // 3072

// workspace layout (bytes) -- keep the historical region map; new buffers alias
// the dead Kt/Vt regions.
#define OFF_XB    0ull                                  // x bf16 [M][1024]
#define OFF_WQKVT (OFF_XB    + (size_t)M_*D_*2)         // Wqkv^T bf16 [3072][1024]
#define OFF_WOT   (OFF_WQKVT + (size_t)N1_*D_*2)        // Wo^T bf16 [1024][1024]
#define OFF_QBUF  (OFF_WOT   + (size_t)D_*D_*2)         // Q bf16 [M][1024] (elu+1; later scaled to Q~)
#define OFF_KT    (OFF_QBUF  + (size_t)M_*D_*2)         // 32 MB region
#define OFF_VT    (OFF_KT    + (size_t)M_*D_*2)         // 32 MB region
#define OFF_KV    (OFF_VT    + (size_t)M_*D_*2)         // 4 MB region (legacy)
#define OFF_KSUM  (OFF_KV    + (size_t)4*64*4096*4)
#define WS_NEEDED (OFF_KSUM  + (size_t)4*64*64*4)
// aliases:
#define OFF_WT    OFF_KT                                 // W~T bf16 [4][1024][1024] = 8 MB
#define OFF_KVS   (OFF_KT + ((size_t)8<<20))             // KV summed fp32 [64 bh][4096] = 1 MB
#define OFF_KSG   (OFF_KT + ((size_t)9<<20))             // Ksum fp32 [64 bh][64] = 16 KB
#define OFF_KVPP  OFF_VT                                 // KV partials fp32 [64 mb][16 ph][4096] = 16 MB
#define OFF_KSPP  (OFF_VT + ((size_t)16<<20))            // Ksum partials fp32 [64 mb][16 ph][64] = 256 KB

// ---------------- merged prep: x->bf16, Wqkv^T, Wo^T (block-range switch) ----------------
__global__ __launch_bounds__(256) void prep_kernel(const float* __restrict__ x, u16* __restrict__ xb,
                                                   const float* __restrict__ Wqkv, u16* __restrict__ wqkvt,
                                                   const float* __restrict__ Wo, u16* __restrict__ wot)
{
  __shared__ float tile[32][33];
  int bid = blockIdx.x, tid = threadIdx.x;
  if (bid < 16384) {
    int i = bid * 256 + tid;               // n4 = M_*D_/4 = 4194304 = 16384*256 exactly
    float4 v = ((const float4*)x)[i];
    uint2 o;
    o.x = (unsigned)f2bf(v.x) | ((unsigned)f2bf(v.y) << 16);
    o.y = (unsigned)f2bf(v.z) | ((unsigned)f2bf(v.w) << 16);
    ((uint2*)xb)[i] = o;
    return;
  }
  const float* in; u16* out; int R, C, cb, rb;
  if (bid < 19456) {
    int t = bid - 16384;  in = Wqkv; out = wqkvt; R = D_; C = N1_;
    cb = t % 96; rb = t / 96;
  } else {
    int t = bid - 19456;  in = Wo; out = wot; R = D_; C = D_;
    cb = t % 32; rb = t / 32;
  }
  int tx = tid & 31, ty = tid >> 5;
  int c0 = cb * 32, r0 = rb * 32;
#pragma unroll
  for (int i = 0; i < 4; i++)
    tile[ty + i*8][tx] = in[(size_t)(r0 + ty + i*8) * C + c0 + tx];
  __syncthreads();
#pragma unroll
  for (int i = 0; i < 4; i++)
    out[(size_t)(c0 + ty + i*8) * R + r0 + tx] = f2bf(tile[tx][ty + i*8]);
}

// ---------------- main GEMM: 256x256 tile, BK=32, ring-4 LDS pipeline ----------------
// C[M,N] = A[M,K](bf16) * Bt[N,K](bf16)^T.  512 thr = 8 waves (2M x 4N); acc 8x4 frags.
// MODE is compile-time (r6 lesson: runtime mode in the address chain cost 27%).
// MODE 1: Q-only qkv (grid.x=4): B rows bn+r; epilogue Q elu+1 -> qout.
// MODE 3: KV-fused qkv (grid.x=8=head-pair p): B rows {1024+p*128 (K), +1024 (V)};
//         epilogue writes K(elu)/V tiles to smem (main-loop layout), computes
//         head-blocked KV + Ksum via MFMA, plain-stores per-M-block partials.
// MODE 2: out-proj (grid.x=4): per-batch B base (bm>>12)<<20 elems; fp32 C store.
// REGISTER NOTE: acc[8][4] = 128 unified regs alone -> NEVER set min-waves > 2
// (r4 lesson: launch_bounds(512,4) caps unified VGPR+AGPR at 128 -> spill, 13x slower).
// Ring-4 ledger: stage t+3 into slot (t+3)&3 (freed by barrier of t-1); end-of-step
// vmcnt(8) -> tile t+1 landed, t+2/t+3 in flight; drain tail 8/4/0.
// LDS per 16KB panel: paired rows [128 phys rows][8 chunks of 16B];
// logical (r,kchunk) at phys chunk pch = (((r&1)<<2)|kchunk) ^ ((r>>1)&7).
// XOR involution applied to global fetch addr on staging and ds_read addr on frag
// read -> conflict-free (verified: 0 bank conflicts).
template<int MODE>
__global__ __launch_bounds__(512, 2) void gemm256(
    const u16* __restrict__ A, const u16* __restrict__ Bt,
    float* __restrict__ Cf, u16* __restrict__ qout,
    float* __restrict__ P1, float* __restrict__ P2,
    int M, int N, int K)
{
  __shared__ __align__(16) char smem[131072];   // [4 slots][A 16KB] + [4 slots][B 16KB]
  int tid = threadIdx.x;
  int w = tid >> 6, lane = tid & 63;
  int quad = lane >> 4, l16 = lane & 15;
  int wm = w >> 2, wn = w & 3;

  // XCD-aware bijective swizzle (nwg % 8 == 0). Blocks with flat%8==x get a
  // contiguous wg chunk -> by-grouped per XCD -> A panel 4MB/XCD (L2-fit).
  int nwg = gridDim.x * gridDim.y;
  int flat = blockIdx.y * gridDim.x + blockIdx.x;
  int wg = (flat & 7) * (nwg >> 3) + (flat >> 3);
  int bx = wg % gridDim.x, by = wg / gridDim.x;
  int bm = by * 256, bn = bx * 256;

  // staging: lane covers LDS bytes lane*16 in its wave's 1KB strip; inverse swizzle
  // goes into the global source address (rule #21: linear dest + inverse-swz source).
  int prl = lane >> 3;                          // phys row-in-strip 0..7
  int c4  = (lane & 7) ^ prl;                   // logical chunk 0..7
  int r0  = ((w << 3) + prl) * 2 + (c4 >> 2);   // logical row 0..127
  int koff = (c4 & 3) * 8;                      // logical k element offset
  const u16* gA0 = A + (size_t)(bm + r0) * K + koff;
  const u16* gB0;
  size_t rowskipA = (size_t)128 * K;
  size_t rowskipB;
  if constexpr (MODE == 3) {
    gB0 = Bt + (size_t)(1024 + bx * 128 + r0) * K + koff;   // K rows; +rowskipB = V rows
    rowskipB = (size_t)1024 * K;
  } else if constexpr (MODE == 2) {
    gB0 = Bt + ((size_t)(bm >> 12) << 20) + (size_t)(bn + r0) * K + koff;
    rowskipB = (size_t)128 * K;
  } else {
    gB0 = Bt + (size_t)(bn + r0) * K + koff;
    rowskipB = (size_t)128 * K;
  }
  char* smemc = smem;
  int ldsAw = w * 1024;                         // wave-uniform LDS bases
  int ldsBw = 65536 + w * 1024;

  // fragment read bases: pr&7 = (l16>>1)&7 (mi*8, wm*64 vanish mod 8)
  int ph = (((l16 & 1) << 2) | quad) ^ ((l16 >> 1) & 7);
  int baseA = wm * 8192 + (l16 >> 1) * 128 + ph * 16;
  int baseB = 65536 + wn * 4096 + (l16 >> 1) * 128 + ph * 16;

  f32x4 acc[8][4];
#pragma unroll
  for (int i = 0; i < 8; i++)
#pragma unroll
    for (int j = 0; j < 4; j++) acc[i][j] = (f32x4)0.0f;

  int nt = K >> 5;   // K=1024 -> 32 steps

#define STG(tt, slot) {                                                   \
    const u16* a0_ = gA0 + (tt) * 32;                                     \
    const u16* b0_ = gB0 + (tt) * 32;                                     \
    gload16(a0_,            smemc + (slot)*16384 + ldsAw);                \
    gload16(a0_ + rowskipA, smemc + (slot)*16384 + 8192 + ldsAw);         \
    gload16(b0_,            smemc + (slot)*16384 + ldsBw);                \
    gload16(b0_ + rowskipB, smemc + (slot)*16384 + 8192 + ldsBw);         \
  }

#define COMPUTE(slot) {                                                              \
    const char* sb = smemc + (slot) * 16384;                                         \
    short8 bfr[4], af[8];                                                            \
    _Pragma("unroll")                                                                \
    for (int nj = 0; nj < 4; nj++) bfr[nj] = *(const short8*)(sb + baseB + nj*1024); \
    _Pragma("unroll")                                                                \
    for (int mi = 0; mi < 8; mi++) af[mi] = *(const short8*)(sb + baseA + mi*1024);  \
    __builtin_amdgcn_s_setprio(1);                                                   \
    _Pragma("unroll")                                                                \
    for (int mi = 0; mi < 8; mi++)                                                   \
      _Pragma("unroll")                                                              \
      for (int nj = 0; nj < 4; nj++)                                                 \
        acc[mi][nj] = __builtin_amdgcn_mfma_f32_16x16x32_bf16(af[mi], bfr[nj],       \
                                                              acc[mi][nj], 0, 0, 0); \
    __builtin_amdgcn_s_setprio(0);                                                   \
  }

#define WAITBAR(n) {                                                      \
    asm volatile("s_waitcnt vmcnt(" #n ")" ::: "memory");                 \
    __builtin_amdgcn_s_barrier();                                         \
    asm volatile("" ::: "memory");                                        \
  }

  // prologue: 3 tiles in flight; wait for tile 0 only
  STG(0, 0); STG(1, 1); STG(2, 2);
  WAITBAR(8)

  // main loop: steps 0 .. nt-5; STG(t+3) always valid (t+3 <= nt-2)
  for (int tb = 0; tb < nt - 4; tb += 4) {
#pragma unroll
    for (int i = 0; i < 4; ++i) {
      int t = tb + i;
      STG(t + 3, ((i + 3) & 3));        // slot (t-1)&3: freed by preceding barrier
      COMPUTE(i)
      WAITBAR(8)                        // t+2, t+3 stay in flight; t+1 landed
    }
  }

  // drain tail: steps nt-4 .. nt-1 in slots 0..3, wait counts shrink 8/4/0
  STG(nt - 1, 3);                       // slot 3 freed by last main-loop barrier
  COMPUTE(0)
  WAITBAR(8)                            // nt-3,nt-2,nt-1 outstanding(12) -> nt-3 landed
  COMPUTE(1)
  WAITBAR(4)                            // nt-2,nt-1 outstanding(8) -> nt-2 landed
  COMPUTE(2)
  WAITBAR(0)                            // nt-1 landed
  COMPUTE(3)

#undef STG
#undef COMPUTE
#undef WAITBAR

  // C/D layout: col = lane&15 (+nj*16), row = quad*4 + reg (verified m89/m91)
  if constexpr (MODE == 2) {
    int colbase = bn + wn * 64;
#pragma unroll
    for (int mi = 0; mi < 8; mi++) {
      int row0 = bm + wm * 128 + mi * 16 + quad * 4;
#pragma unroll
      for (int nj = 0; nj < 4; nj++) {
        int col = colbase + nj * 16 + l16;
#pragma unroll
        for (int r = 0; r < 4; r++)
          Cf[(size_t)(row0 + r) * N + col] = acc[mi][nj][r];
      }
    }
  } else if constexpr (MODE == 1) {
#pragma unroll
    for (int mi = 0; mi < 8; mi++) {
      int row0 = bm + wm * 128 + mi * 16 + quad * 4;
#pragma unroll
      for (int nj = 0; nj < 4; nj++) {
        int col = bn + wn * 64 + nj * 16 + l16;
#pragma unroll
        for (int r = 0; r < 4; r++) {
          float v = acc[mi][nj][r];
          v = (v > 0.0f) ? (v + 1.0f) : __expf(v);   // elu+1
          qout[(size_t)(row0 + r) * D_ + col] = f2bf(v);
        }
      }
    }
  } else {   // MODE 3: fused KV + Ksum
    __syncthreads();   // all waves done with slot-3 ds_reads before smem reuse
    // 1) write K(elu)/V tiles to smem in the main-loop paired-row layout:
    //    8 s-slots x [128 rows][32 s], K at 0, V at 65536.
    {
      char* basekv = smemc + ((wn < 2) ? 0 : 65536);
      bool doElu = (wn < 2);
#pragma unroll
      for (int mi = 0; mi < 8; mi++) {
        int sb = wm * 128 + mi * 16 + quad * 4;
        int slot = sb >> 5;
        int kc = (sb >> 3) & 3;
        int so = (sb & 7) * 2;                   // byte offset within 16B chunk
#pragma unroll
        for (int nj = 0; nj < 4; nj++) {
          int dv = (wn & 1) * 64 + nj * 16 + l16;   // row 0..127 (head = dv>>6)
          int pc = (((dv & 1) << 2) | kc) ^ ((dv >> 1) & 7);
          float v0 = acc[mi][nj][0], v1 = acc[mi][nj][1], v2 = acc[mi][nj][2], v3 = acc[mi][nj][3];
          if (doElu) {
            v0 = (v0 > 0.0f) ? (v0 + 1.0f) : __expf(v0);
            v1 = (v1 > 0.0f) ? (v1 + 1.0f) : __expf(v1);
            v2 = (v2 > 0.0f) ? (v2 + 1.0f) : __expf(v2);
            v3 = (v3 > 0.0f) ? (v3 + 1.0f) : __expf(v3);
          }
          uint2 o;
          o.x = (unsigned)f2bf(v0) | ((unsigned)f2bf(v1) << 16);
          o.y = (unsigned)f2bf(v2) | ((unsigned)f2bf(v3) << 16);
          *(uint2*)(basekv + slot*8192 + (dv >> 1)*128 + pc*16 + so) = o;
        }
      }
    }
    __syncthreads();
    // 2) head-blocked KV: wave w -> head hh=w>>2, d-half dh=w&1, v-half vh=(w>>1)&1.
    //    KV[d][v] = sum_s K[s,d]V[s,v]; Ksum[d] via ones-MFMA (kv_kernel pattern).
    int hh = w >> 2, dh = w & 1, vh = (w >> 1) & 1;
    short8 ones;
#pragma unroll
    for (int e = 0; e < 8; ++e) ones[e] = (short)0x3F80;   // bf16 1.0
    f32x4 a2[2][2], s2[2];
#pragma unroll
    for (int i = 0; i < 2; i++) {
      s2[i] = (f32x4)0.0f;
#pragma unroll
      for (int j = 0; j < 2; j++) a2[i][j] = (f32x4)0.0f;
    }
#pragma unroll
    for (int t = 0; t < 8; t++) {
      short8 ak[2], bv[2];
#pragma unroll
      for (int i = 0; i < 2; i++) {
        int d = hh * 64 + dh * 32 + i * 16 + l16;
        ak[i] = *(const short8*)(smemc + t*8192 + (d >> 1)*128 +
                                 (((((d & 1) << 2) | quad)) ^ ((d >> 1) & 7))*16);
        int v = hh * 64 + vh * 32 + i * 16 + l16;
        bv[i] = *(const short8*)(smemc + 65536 + t*8192 + (v >> 1)*128 +
                                 (((((v & 1) << 2) | quad)) ^ ((v >> 1) & 7))*16);
      }
#pragma unroll
      for (int i = 0; i < 2; i++) {
#pragma unroll
        for (int j = 0; j < 2; j++)
          a2[i][j] = __builtin_amdgcn_mfma_f32_16x16x32_bf16(ak[i], bv[j], a2[i][j], 0, 0, 0);
        if (vh == 0)
          s2[i] = __builtin_amdgcn_mfma_f32_16x16x32_bf16(ak[i], ones, s2[i], 0, 0, 0);
      }
    }
    // 3) plain partial stores: kvpp[mb*16 + p*2 + hh][dl*64+vl], kspp[...][dl]
    int p = bx;                 // head pair 0..7
    int mb = bm >> 8;           // M-block 0..63
    float* kdst = P1 + (size_t)(mb * 16 + p * 2 + hh) * 4096;
#pragma unroll
    for (int i = 0; i < 2; i++)
#pragma unroll
      for (int j = 0; j < 2; j++)
#pragma unroll
        for (int r = 0; r < 4; r++)
          kdst[(dh*32 + i*16 + quad*4 + r) * 64 + vh*32 + j*16 + l16] = a2[i][j][r];
    if (vh == 0 && l16 == 0) {
      float* sdst = P2 + (size_t)(mb * 16 + p * 2 + hh) * 64;
#pragma unroll
      for (int i = 0; i < 2; i++)
#pragma unroll
        for (int r = 0; r < 4; r++)
          sdst[dh*32 + i*16 + quad*4 + r] = s2[i][r];
    }
  }
}

// ---------------- kvsum: kvp[bh] = sum over the batch's 16 M-blocks of kvpp ----------------
__global__ __launch_bounds__(256) void kvsum_kernel(const float* __restrict__ kvpp,
                                                    const float* __restrict__ kspp,
                                                    float* __restrict__ kvp,
                                                    float* __restrict__ ksg)
{
  int tid = threadIdx.x, bh = blockIdx.x;
  int b = bh >> 4, phh = bh & 15;                 // phh = p*2+hh
  int base = b * 256 + phh;                       // partial idx for mb = b*16
  for (int i = tid; i < 4096; i += 256) {
    float s = 0.0f;
#pragma unroll
    for (int m = 0; m < 16; ++m)
      s += kvpp[(size_t)(base + m * 16) * 4096 + i];
    kvp[(size_t)bh * 4096 + i] = s;
  }
  if (tid < 64) {
    float s = 0.0f;
#pragma unroll
    for (int m = 0; m < 16; ++m)
      s += kspp[(size_t)(base + m * 16) * 64 + tid];
    ksg[bh * 64 + tid] = s;
  }
}

// ---------------- kvw: W~T[b][c][h*64+d] = sum_v KV_bh[d,v] * Wo[h*64+v, c] ----------------
// out = sum_h diag(1/n_h) Q_h KV_h Wo_h = Q~ @ W~_b. A = wot rows c, B = KV rows d
// -> D[row=c,col=d]; stores W~T[c][hd]. Grid (8 c-tiles, 64 bh); 4 waves.
__global__ __launch_bounds__(256) void kvw_kernel(const float* __restrict__ kvp,
                                                  const u16* __restrict__ wot,
                                                  u16* __restrict__ wt)
{
  __shared__ u16 kvlds[4096];   // KV_bh [d][v] bf16
  int tid = threadIdx.x;
  int ct = blockIdx.x;          // c-tile 0..7
  int bh = blockIdx.y;          // 0..63
  int b = bh >> 4, h = bh & 15;
  const float* kvsrc = kvp + (size_t)bh * 4096;
  for (int i = tid; i < 4096; i += 256) kvlds[i] = f2bf(kvsrc[i]);
  __syncthreads();
  int w = tid >> 6, lane = tid & 63, quad = lane >> 4, l16 = lane & 15;

  short8 bfr[2][4];
#pragma unroll
  for (int ks = 0; ks < 2; ++ks)
#pragma unroll
    for (int nj = 0; nj < 4; ++nj)
      bfr[ks][nj] = *(const short8*)(&kvlds[(nj*16 + l16) * 64 + ks*32 + quad*8]);

  f32x4 acc[2][4];
#pragma unroll
  for (int i = 0; i < 2; i++)
#pragma unroll
    for (int j = 0; j < 4; j++) acc[i][j] = (f32x4)0.0f;

  int c0 = ct * 128 + w * 32;
#pragma unroll
  for (int ks = 0; ks < 2; ++ks) {
#pragma unroll
    for (int mi = 0; mi < 2; ++mi) {
      short8 af = *(const short8*)(wot + (size_t)(c0 + mi*16 + l16) * 1024 + h*64 + ks*32 + quad*8);
#pragma unroll
      for (int nj = 0; nj < 4; ++nj)
        acc[mi][nj] = __builtin_amdgcn_mfma_f32_16x16x32_bf16(af, bfr[ks][nj], acc[mi][nj], 0, 0, 0);
    }
  }
  u16* dst = wt + ((size_t)b << 20);
#pragma unroll
  for (int mi = 0; mi < 2; ++mi) {
    int c = c0 + mi*16 + quad*4;
#pragma unroll
    for (int nj = 0; nj < 4; ++nj) {
      int hd = h*64 + nj*16 + l16;
#pragma unroll
      for (int r = 0; r < 4; ++r)
        dst[(size_t)(c + r) * 1024 + hd] = f2bf(acc[mi][nj][r]);
    }
  }
}

// ---------------- qscale: qbuf[s, h*64+d] /= (sum_d' qbuf[s,h*64+d']*ksum_bh[d'] + eps) ----------------
__global__ __launch_bounds__(256) void qscale_kernel(u16* __restrict__ qbuf,
                                                     const float* __restrict__ ksum)
{
  __shared__ float ks[1024];
  int tid = threadIdx.x;
  int blk = blockIdx.x;          // 4096 blocks
  int b = blk >> 10;             // 1024 blocks per batch
  for (int i = tid; i < 1024; i += 256) ks[i] = ksum[b * 1024 + i];
  __syncthreads();
  int wv = tid >> 6, ln = tid & 63;
  int s = blk * 4 + wv;
  u16* row = qbuf + (size_t)s * 1024 + ln * 16;
  short8 qa = *(const short8*)row;
  short8 qb = *(const short8*)(row + 8);
  int h4 = (ln >> 2) * 64 + (ln & 3) * 16;   // ksum base for this lane's 16 elems
  float p = 0.0f;
#pragma unroll
  for (int j = 0; j < 8; ++j) p += bf2f((u16)qa[j]) * ks[h4 + j];
#pragma unroll
  for (int j = 0; j < 8; ++j) p += bf2f((u16)qb[j]) * ks[h4 + 8 + j];
  p += __shfl_xor(p, 1);
  p += __shfl_xor(p, 2);                     // all 4 lanes of the head-group hold n_h
  float inv = 1.0f / (p + 1e-6f);
  short8 oa, ob;
#pragma unroll
  for (int j = 0; j < 8; ++j) {
    oa[j] = (short)f2bf(bf2f((u16)qa[j]) * inv);
    ob[j] = (short)f2bf(bf2f((u16)qb[j]) * inv);
  }
  *(short8*)row = oa;
  *(short8*)(row + 8) = ob;
}

extern "C" void kernel_launch(void* const* d_in, const int* in_sizes, int n_in,
                              void* d_out, int out_size, void* d_ws, size_t ws_size,
                              hipStream_t stream) {
  const float* x    = (const float*)d_in[0];
  const float* Wqkv = (const float*)d_in[1];
  const float* Wo   = (const float*)d_in[2];
  float* out = (float*)d_out;
  char* ws = (char*)d_ws;
  if (ws_size < WS_NEEDED) return;  // visible failure, no corruption

  u16*   xb    = (u16*)  (ws + OFF_XB);
  u16*   wqkvt = (u16*)  (ws + OFF_WQKVT);
  u16*   wot   = (u16*)  (ws + OFF_WOT);
  u16*   qbuf  = (u16*)  (ws + OFF_QBUF);
  u16*   wt    = (u16*)  (ws + OFF_WT);
  float* kvs   = (float*)(ws + OFF_KVS);
  float* ksg   = (float*)(ws + OFF_KSG);
  float* kvpp  = (float*)(ws + OFF_KVPP);
  float* kspp  = (float*)(ws + OFF_KSPP);

  prep_kernel<<<20480, 256, 0, stream>>>(x, xb, Wqkv, wqkvt, Wo, wot);
  // K/V columns: fused KV+Ksum partials (no Kt/Vt materialization)
  gemm256<3><<<dim3(8, M_/256), 512, 0, stream>>>(xb, wqkvt, nullptr, nullptr, kvpp, kspp,
                                                  M_, N1_, D_);
  // Q columns: elu+1 -> qbuf
  gemm256<1><<<dim3(4, M_/256), 512, 0, stream>>>(xb, wqkvt, nullptr, qbuf, nullptr, nullptr,
                                                  M_, N1_, D_);
  // sum the 16 per-batch partials -> kvp + ksg
  kvsum_kernel<<<64, 256, 0, stream>>>(kvpp, kspp, kvs, ksg);
  // W~T precompute (per-batch KV @ Wo)
  kvw_kernel<<<dim3(8, 64), 256, 0, stream>>>(kvs, wot, wt);
  // Q~ = Q / (Q.Ksum + eps), in place
  qscale_kernel<<<4096, 256, 0, stream>>>(qbuf, ksg);
  // out = Q~ @ W~_b (per-batch B via compile-time MODE=2), fp32 out
  gemm256<2><<<dim3(4, M_/256), 512, 0, stream>>>(qbuf, wt, out, nullptr, nullptr, nullptr,
                                                  M_, D_, D_);
}

// Round 9
// 288.747 us; speedup vs baseline: 1.1698x; 1.0154x over previous
//
#include <hip/hip_runtime.h>

using u16 = unsigned short;
typedef __attribute__((ext_vector_type(8))) short short8;
typedef __attribute__((ext_vector_type(4))) float f32x4;

__device__ __forceinline__ u16 f2bf(float f) {
  unsigned int u = __float_as_uint(f);
  u = (u + 0x7FFFu + ((u >> 16) & 1u)) >> 16;   // RNE, fine for non-NaN
  return (u16)u;
}
__device__ __forceinline__ float bf2f(u16 v) {
  return __uint_as_float(((unsigned int)v) << 16);
}

// async global->LDS, 16B per lane. LDS dest is wave-uniform base + lane*16.
__device__ __forceinline__ void gload16(const void* g, void* l) {
  __builtin_amdgcn_global_load_lds((const __attribute__((address_space(1))) void*)g,
                                   (__attribute__((address_space(3))) void*)l, 16, 0, 0);
}

#define B_ 4
#define S_ 4096
#define D_ 1024
#define H_ 16
#define HD_ 64
#define M_ (B_*S_)    // 16384
#define N1_ (3*D_)    // 3072

// workspace layout (bytes) -- historical region map; new buffers alias dead regions.
#define OFF_XB    0ull                                  // x bf16 [M][1024]
#define OFF_WQKVT (OFF_XB    + (size_t)M_*D_*2)         // Wqkv^T bf16 [3072][1024]
#define OFF_WOT   (OFF_WQKVT + (size_t)N1_*D_*2)        // Wo^T bf16 [1024][1024]
#define OFF_QBUF  (OFF_WOT   + (size_t)D_*D_*2)         // Q~ bf16 [M][1024] (elu+1, pre-scaled)
#define OFF_KT    (OFF_QBUF  + (size_t)M_*D_*2)         // 32 MB region
#define OFF_VT    (OFF_KT    + (size_t)M_*D_*2)         // 32 MB region
#define OFF_KV    (OFF_VT    + (size_t)M_*D_*2)         // 4 MB region (legacy)
#define OFF_KSUM  (OFF_KV    + (size_t)4*64*4096*4)
#define WS_NEEDED (OFF_KSUM  + (size_t)4*64*64*4)
// aliases:
#define OFF_WT    OFF_KT                                 // W~T bf16 [4][1024][1024] = 8 MB
#define OFF_KSG   (OFF_KT + ((size_t)9<<20))             // Ksum fp32 [64 bh][64] = 16 KB
#define OFF_KVPP  OFF_VT                                 // KV partials fp32 [64 mb][16 h][4096] = 16 MB
#define OFF_KSPP  (OFF_VT + ((size_t)16<<20))            // Ksum partials fp32 [64 mb][16 h][64] = 256 KB

// ---------------- merged prep: x->bf16, Wqkv^T, Wo^T (block-range switch) ----------------
__global__ __launch_bounds__(256) void prep_kernel(const float* __restrict__ x, u16* __restrict__ xb,
                                                   const float* __restrict__ Wqkv, u16* __restrict__ wqkvt,
                                                   const float* __restrict__ Wo, u16* __restrict__ wot)
{
  __shared__ float tile[32][33];
  int bid = blockIdx.x, tid = threadIdx.x;
  if (bid < 16384) {
    int i = bid * 256 + tid;               // n4 = M_*D_/4 = 4194304 = 16384*256 exactly
    float4 v = ((const float4*)x)[i];
    uint2 o;
    o.x = (unsigned)f2bf(v.x) | ((unsigned)f2bf(v.y) << 16);
    o.y = (unsigned)f2bf(v.z) | ((unsigned)f2bf(v.w) << 16);
    ((uint2*)xb)[i] = o;
    return;
  }
  const float* in; u16* out; int R, C, cb, rb;
  if (bid < 19456) {
    int t = bid - 16384;  in = Wqkv; out = wqkvt; R = D_; C = N1_;
    cb = t % 96; rb = t / 96;
  } else {
    int t = bid - 19456;  in = Wo; out = wot; R = D_; C = D_;
    cb = t % 32; rb = t / 32;
  }
  int tx = tid & 31, ty = tid >> 5;
  int c0 = cb * 32, r0 = rb * 32;
#pragma unroll
  for (int i = 0; i < 4; i++)
    tile[ty + i*8][tx] = in[(size_t)(r0 + ty + i*8) * C + c0 + tx];
  __syncthreads();
#pragma unroll
  for (int i = 0; i < 4; i++)
    out[(size_t)(c0 + ty + i*8) * R + r0 + tx] = f2bf(tile[tx][ty + i*8]);
}

// ---------------- main GEMM: 256x256 tile, BK=32, ring-4 LDS pipeline ----------------
// C[M,N] = A[M,K](bf16) * Bt[N,K](bf16)^T.  512 thr = 8 waves (2M x 4N); acc 8x4 frags.
// MODE is compile-time (r6 lesson: runtime mode in the address chain cost 27%).
// MODE 4: Q qkv (grid.x=4) with FUSED per-head normalizer: each wave's 64-col
//         subtile = one head -> n_h per row via lane-partial dot + 4x shfl_xor
//         (l16-group = one row), then scaled elu+1 Q~ -> qout. Needs Ks (ksg).
// MODE 3: KV-fused qkv (grid.x=8=head-pair p): B rows {1024+p*128 (K), +1024 (V)};
//         epilogue writes K(elu)/V tiles to smem (main-loop layout), computes
//         head-blocked KV + Ksum via MFMA, plain-stores per-M-block partials.
// MODE 2: out-proj (grid.x=4): per-batch B base (bm>>12)<<20 elems; fp32 C store.
// REGISTER NOTE: acc[8][4] = 128 unified regs alone -> NEVER set min-waves > 2
// (r4 lesson: launch_bounds(512,4) caps unified VGPR+AGPR at 128 -> spill, 13x slower).
// Ring-4 ledger: stage t+3 into slot (t+3)&3 (freed by barrier of t-1); end-of-step
// vmcnt(8) -> tile t+1 landed, t+2/t+3 in flight; drain tail 8/4/0.
// LDS per 16KB panel: paired rows [128 phys rows][8 chunks of 16B];
// logical (r,kchunk) at phys chunk pch = (((r&1)<<2)|kchunk) ^ ((r>>1)&7).
// XOR involution applied to global fetch addr on staging and ds_read addr on frag
// read -> conflict-free (verified: 0 bank conflicts in main loop).
template<int MODE>
__global__ __launch_bounds__(512, 2) void gemm256(
    const u16* __restrict__ A, const u16* __restrict__ Bt,
    float* __restrict__ Cf, u16* __restrict__ qout,
    float* __restrict__ P1, float* __restrict__ P2,
    const float* __restrict__ Ks,
    int M, int N, int K)
{
  __shared__ __align__(16) char smem[131072];   // [4 slots][A 16KB] + [4 slots][B 16KB]
  int tid = threadIdx.x;
  int w = tid >> 6, lane = tid & 63;
  int quad = lane >> 4, l16 = lane & 15;
  int wm = w >> 2, wn = w & 3;

  // XCD-aware bijective swizzle (nwg % 8 == 0). Blocks with flat%8==x get a
  // contiguous wg chunk -> by-grouped per XCD -> A panel 4MB/XCD (L2-fit).
  int nwg = gridDim.x * gridDim.y;
  int flat = blockIdx.y * gridDim.x + blockIdx.x;
  int wg = (flat & 7) * (nwg >> 3) + (flat >> 3);
  int bx = wg % gridDim.x, by = wg / gridDim.x;
  int bm = by * 256, bn = bx * 256;

  // staging: lane covers LDS bytes lane*16 in its wave's 1KB strip; inverse swizzle
  // goes into the global source address (rule #21: linear dest + inverse-swz source).
  int prl = lane >> 3;                          // phys row-in-strip 0..7
  int c4  = (lane & 7) ^ prl;                   // logical chunk 0..7
  int r0  = ((w << 3) + prl) * 2 + (c4 >> 2);   // logical row 0..127
  int koff = (c4 & 3) * 8;                      // logical k element offset
  const u16* gA0 = A + (size_t)(bm + r0) * K + koff;
  const u16* gB0;
  size_t rowskipA = (size_t)128 * K;
  size_t rowskipB;
  if constexpr (MODE == 3) {
    gB0 = Bt + (size_t)(1024 + bx * 128 + r0) * K + koff;   // K rows; +rowskipB = V rows
    rowskipB = (size_t)1024 * K;
  } else if constexpr (MODE == 2) {
    gB0 = Bt + ((size_t)(bm >> 12) << 20) + (size_t)(bn + r0) * K + koff;
    rowskipB = (size_t)128 * K;
  } else {
    gB0 = Bt + (size_t)(bn + r0) * K + koff;
    rowskipB = (size_t)128 * K;
  }
  char* smemc = smem;
  int ldsAw = w * 1024;                         // wave-uniform LDS bases
  int ldsBw = 65536 + w * 1024;

  // fragment read bases: pr&7 = (l16>>1)&7 (mi*8, wm*64 vanish mod 8)
  int ph = (((l16 & 1) << 2) | quad) ^ ((l16 >> 1) & 7);
  int baseA = wm * 8192 + (l16 >> 1) * 128 + ph * 16;
  int baseB = 65536 + wn * 4096 + (l16 >> 1) * 128 + ph * 16;

  f32x4 acc[8][4];
#pragma unroll
  for (int i = 0; i < 8; i++)
#pragma unroll
    for (int j = 0; j < 4; j++) acc[i][j] = (f32x4)0.0f;

  int nt = K >> 5;   // K=1024 -> 32 steps

#define STG(tt, slot) {                                                   \
    const u16* a0_ = gA0 + (tt) * 32;                                     \
    const u16* b0_ = gB0 + (tt) * 32;                                     \
    gload16(a0_,            smemc + (slot)*16384 + ldsAw);                \
    gload16(a0_ + rowskipA, smemc + (slot)*16384 + 8192 + ldsAw);         \
    gload16(b0_,            smemc + (slot)*16384 + ldsBw);                \
    gload16(b0_ + rowskipB, smemc + (slot)*16384 + 8192 + ldsBw);         \
  }

#define COMPUTE(slot) {                                                              \
    const char* sb = smemc + (slot) * 16384;                                         \
    short8 bfr[4], af[8];                                                            \
    _Pragma("unroll")                                                                \
    for (int nj = 0; nj < 4; nj++) bfr[nj] = *(const short8*)(sb + baseB + nj*1024); \
    _Pragma("unroll")                                                                \
    for (int mi = 0; mi < 8; mi++) af[mi] = *(const short8*)(sb + baseA + mi*1024);  \
    __builtin_amdgcn_s_setprio(1);                                                   \
    _Pragma("unroll")                                                                \
    for (int mi = 0; mi < 8; mi++)                                                   \
      _Pragma("unroll")                                                              \
      for (int nj = 0; nj < 4; nj++)                                                 \
        acc[mi][nj] = __builtin_amdgcn_mfma_f32_16x16x32_bf16(af[mi], bfr[nj],       \
                                                              acc[mi][nj], 0, 0, 0); \
    __builtin_amdgcn_s_setprio(0);                                                   \
  }

#define WAITBAR(n) {                                                      \
    asm volatile("s_waitcnt vmcnt(" #n ")" ::: "memory");                 \
    __builtin_amdgcn_s_barrier();                                         \
    asm volatile("" ::: "memory");                                        \
  }

  // prologue: 3 tiles in flight; wait for tile 0 only
  STG(0, 0); STG(1, 1); STG(2, 2);
  WAITBAR(8)

  // main loop: steps 0 .. nt-5; STG(t+3) always valid (t+3 <= nt-2)
  for (int tb = 0; tb < nt - 4; tb += 4) {
#pragma unroll
    for (int i = 0; i < 4; ++i) {
      int t = tb + i;
      STG(t + 3, ((i + 3) & 3));        // slot (t-1)&3: freed by preceding barrier
      COMPUTE(i)
      WAITBAR(8)                        // t+2, t+3 stay in flight; t+1 landed
    }
  }

  // drain tail: steps nt-4 .. nt-1 in slots 0..3, wait counts shrink 8/4/0
  STG(nt - 1, 3);                       // slot 3 freed by last main-loop barrier
  COMPUTE(0)
  WAITBAR(8)                            // nt-3,nt-2,nt-1 outstanding(12) -> nt-3 landed
  COMPUTE(1)
  WAITBAR(4)                            // nt-2,nt-1 outstanding(8) -> nt-2 landed
  COMPUTE(2)
  WAITBAR(0)                            // nt-1 landed
  COMPUTE(3)

#undef STG
#undef COMPUTE
#undef WAITBAR

  // C/D layout: col = lane&15 (+nj*16), row = quad*4 + reg (verified m89/m91)
  if constexpr (MODE == 2) {
    int colbase = bn + wn * 64;
#pragma unroll
    for (int mi = 0; mi < 8; mi++) {
      int row0 = bm + wm * 128 + mi * 16 + quad * 4;
#pragma unroll
      for (int nj = 0; nj < 4; nj++) {
        int col = colbase + nj * 16 + l16;
#pragma unroll
        for (int r = 0; r < 4; r++)
          Cf[(size_t)(row0 + r) * N + col] = acc[mi][nj][r];
      }
    }
  } else if constexpr (MODE == 4) {
    // Q with fused per-head normalizer scale. colbase is one full head.
    int colbase = bn + wn * 64;
    int b = bm >> 12;
    int h = colbase >> 6;
    float ksv[4];
#pragma unroll
    for (int nj = 0; nj < 4; nj++)
      ksv[nj] = Ks[(b * 16 + h) * 64 + nj * 16 + l16];
#pragma unroll
    for (int mi = 0; mi < 8; mi++) {
      float vv[4][4], nrm[4];
#pragma unroll
      for (int r = 0; r < 4; r++) nrm[r] = 0.0f;
#pragma unroll
      for (int nj = 0; nj < 4; nj++)
#pragma unroll
        for (int r = 0; r < 4; r++) {
          float v = acc[mi][nj][r];
          v = (v > 0.0f) ? (v + 1.0f) : __expf(v);   // elu+1
          vv[nj][r] = v;
          nrm[r] += v * ksv[nj];
        }
      // reduce over the 16 l16-lanes (same row, 64 cols of the head)
#pragma unroll
      for (int r = 0; r < 4; r++) {
        nrm[r] += __shfl_xor(nrm[r], 1);
        nrm[r] += __shfl_xor(nrm[r], 2);
        nrm[r] += __shfl_xor(nrm[r], 4);
        nrm[r] += __shfl_xor(nrm[r], 8);
        nrm[r] = 1.0f / (nrm[r] + 1e-6f);
      }
      int row0 = bm + wm * 128 + mi * 16 + quad * 4;
#pragma unroll
      for (int nj = 0; nj < 4; nj++) {
        int col = colbase + nj * 16 + l16;
#pragma unroll
        for (int r = 0; r < 4; r++)
          qout[(size_t)(row0 + r) * D_ + col] = f2bf(vv[nj][r] * nrm[r]);
      }
    }
  } else {   // MODE 3: fused KV + Ksum
    __syncthreads();   // all waves done with slot-3 ds_reads before smem reuse
    // 1) write K(elu)/V tiles to smem in the main-loop paired-row layout:
    //    8 s-slots x [128 rows][32 s], K at 0, V at 65536.
    {
      char* basekv = smemc + ((wn < 2) ? 0 : 65536);
      bool doElu = (wn < 2);
#pragma unroll
      for (int mi = 0; mi < 8; mi++) {
        int sb = wm * 128 + mi * 16 + quad * 4;
        int slot = sb >> 5;
        int kc = (sb >> 3) & 3;
        int so = (sb & 7) * 2;                   // byte offset within 16B chunk
#pragma unroll
        for (int nj = 0; nj < 4; nj++) {
          int dv = (wn & 1) * 64 + nj * 16 + l16;   // row 0..127 (head = dv>>6)
          int pc = (((dv & 1) << 2) | kc) ^ ((dv >> 1) & 7);
          float v0 = acc[mi][nj][0], v1 = acc[mi][nj][1], v2 = acc[mi][nj][2], v3 = acc[mi][nj][3];
          if (doElu) {
            v0 = (v0 > 0.0f) ? (v0 + 1.0f) : __expf(v0);
            v1 = (v1 > 0.0f) ? (v1 + 1.0f) : __expf(v1);
            v2 = (v2 > 0.0f) ? (v2 + 1.0f) : __expf(v2);
            v3 = (v3 > 0.0f) ? (v3 + 1.0f) : __expf(v3);
          }
          uint2 o;
          o.x = (unsigned)f2bf(v0) | ((unsigned)f2bf(v1) << 16);
          o.y = (unsigned)f2bf(v2) | ((unsigned)f2bf(v3) << 16);
          *(uint2*)(basekv + slot*8192 + (dv >> 1)*128 + pc*16 + so) = o;
        }
      }
    }
    __syncthreads();
    // 2) head-blocked KV: wave w -> head hh=w>>2, d-half dh=w&1, v-half vh=(w>>1)&1.
    int hh = w >> 2, dh = w & 1, vh = (w >> 1) & 1;
    short8 ones;
#pragma unroll
    for (int e = 0; e < 8; ++e) ones[e] = (short)0x3F80;   // bf16 1.0
    f32x4 a2[2][2], s2[2];
#pragma unroll
    for (int i = 0; i < 2; i++) {
      s2[i] = (f32x4)0.0f;
#pragma unroll
      for (int j = 0; j < 2; j++) a2[i][j] = (f32x4)0.0f;
    }
#pragma unroll
    for (int t = 0; t < 8; t++) {
      short8 ak[2], bv[2];
#pragma unroll
      for (int i = 0; i < 2; i++) {
        int d = hh * 64 + dh * 32 + i * 16 + l16;
        ak[i] = *(const short8*)(smemc + t*8192 + (d >> 1)*128 +
                                 (((((d & 1) << 2) | quad)) ^ ((d >> 1) & 7))*16);
        int v = hh * 64 + vh * 32 + i * 16 + l16;
        bv[i] = *(const short8*)(smemc + 65536 + t*8192 + (v >> 1)*128 +
                                 (((((v & 1) << 2) | quad)) ^ ((v >> 1) & 7))*16);
      }
#pragma unroll
      for (int i = 0; i < 2; i++) {
#pragma unroll
        for (int j = 0; j < 2; j++)
          a2[i][j] = __builtin_amdgcn_mfma_f32_16x16x32_bf16(ak[i], bv[j], a2[i][j], 0, 0, 0);
        if (vh == 0)
          s2[i] = __builtin_amdgcn_mfma_f32_16x16x32_bf16(ak[i], ones, s2[i], 0, 0, 0);
      }
    }
    // 3) plain partial stores: kvpp[mb*16 + p*2 + hh][dl*64+vl], kspp[...][dl]
    int p = bx;                 // head pair 0..7
    int mb = bm >> 8;           // M-block 0..63
    float* kdst = P1 + (size_t)(mb * 16 + p * 2 + hh) * 4096;
#pragma unroll
    for (int i = 0; i < 2; i++)
#pragma unroll
      for (int j = 0; j < 2; j++)
#pragma unroll
        for (int r = 0; r < 4; r++)
          kdst[(dh*32 + i*16 + quad*4 + r) * 64 + vh*32 + j*16 + l16] = a2[i][j][r];
    if (vh == 0 && l16 == 0) {
      float* sdst = P2 + (size_t)(mb * 16 + p * 2 + hh) * 64;
#pragma unroll
      for (int i = 0; i < 2; i++)
#pragma unroll
        for (int r = 0; r < 4; r++)
          sdst[dh*32 + i*16 + quad*4 + r] = s2[i][r];
    }
  }
}

// ---------------- kvw: sum partials -> KV_bh, Ksum; W~T[b][c][hd] = KV_bh @ Wo_h ----------------
// Merged kvsum+kvw (one launch). Grid 64 (bh = b*16+h); 512 thr = 8 waves.
// Sums the batch's 16 M-block partials into LDS (bf16) + ksg, then each wave
// computes a 128-row c-chunk of W~T via MFMA (A = wot rows c, B = KV rows d
// -> D[row=c,col=d]); 4 sub-chunks of 32 c-rows reuse the verified kvw body.
__global__ __launch_bounds__(512) void kvw_kernel(const float* __restrict__ kvpp,
                                                  const float* __restrict__ kspp,
                                                  const u16* __restrict__ wot,
                                                  u16* __restrict__ wt,
                                                  float* __restrict__ ksg)
{
  __shared__ u16 kvlds[4096];   // KV_bh [d][v] bf16
  int tid = threadIdx.x, bh = blockIdx.x;
  int b = bh >> 4, h = bh & 15;
  for (int i = tid; i < 4096; i += 512) {
    float s = 0.0f;
#pragma unroll
    for (int m = 0; m < 16; ++m)
      s += kvpp[(size_t)(((b * 16 + m) * 16) + h) * 4096 + i];
    kvlds[i] = f2bf(s);
  }
  if (tid < 64) {
    float s = 0.0f;
#pragma unroll
    for (int m = 0; m < 16; ++m)
      s += kspp[(size_t)(((b * 16 + m) * 16) + h) * 64 + tid];
    ksg[bh * 64 + tid] = s;
  }
  __syncthreads();
  int w = tid >> 6, lane = tid & 63, quad = lane >> 4, l16 = lane & 15;

  short8 bfr[2][4];
#pragma unroll
  for (int ks = 0; ks < 2; ++ks)
#pragma unroll
    for (int nj = 0; nj < 4; ++nj)
      bfr[ks][nj] = *(const short8*)(&kvlds[(nj*16 + l16) * 64 + ks*32 + quad*8]);

  u16* dst = wt + ((size_t)b << 20);
#pragma unroll
  for (int cc = 0; cc < 4; ++cc) {
    int c0 = w * 128 + cc * 32;
    f32x4 acc[2][4];
#pragma unroll
    for (int i = 0; i < 2; i++)
#pragma unroll
      for (int j = 0; j < 4; j++) acc[i][j] = (f32x4)0.0f;
#pragma unroll
    for (int ks = 0; ks < 2; ++ks) {
#pragma unroll
      for (int mi = 0; mi < 2; ++mi) {
        short8 af = *(const short8*)(wot + (size_t)(c0 + mi*16 + l16) * 1024 + h*64 + ks*32 + quad*8);
#pragma unroll
        for (int nj = 0; nj < 4; ++nj)
          acc[mi][nj] = __builtin_amdgcn_mfma_f32_16x16x32_bf16(af, bfr[ks][nj], acc[mi][nj], 0, 0, 0);
      }
    }
#pragma unroll
    for (int mi = 0; mi < 2; ++mi) {
      int c = c0 + mi*16 + quad*4;
#pragma unroll
      for (int nj = 0; nj < 4; ++nj) {
        int hd = h*64 + nj*16 + l16;
#pragma unroll
        for (int r = 0; r < 4; ++r)
          dst[(size_t)(c + r) * 1024 + hd] = f2bf(acc[mi][nj][r]);
      }
    }
  }
}

extern "C" void kernel_launch(void* const* d_in, const int* in_sizes, int n_in,
                              void* d_out, int out_size, void* d_ws, size_t ws_size,
                              hipStream_t stream) {
  const float* x    = (const float*)d_in[0];
  const float* Wqkv = (const float*)d_in[1];
  const float* Wo   = (const float*)d_in[2];
  float* out = (float*)d_out;
  char* ws = (char*)d_ws;
  if (ws_size < WS_NEEDED) return;  // visible failure, no corruption

  u16*   xb    = (u16*)  (ws + OFF_XB);
  u16*   wqkvt = (u16*)  (ws + OFF_WQKVT);
  u16*   wot   = (u16*)  (ws + OFF_WOT);
  u16*   qbuf  = (u16*)  (ws + OFF_QBUF);
  u16*   wt    = (u16*)  (ws + OFF_WT);
  float* ksg   = (float*)(ws + OFF_KSG);
  float* kvpp  = (float*)(ws + OFF_KVPP);
  float* kspp  = (float*)(ws + OFF_KSPP);

  prep_kernel<<<20480, 256, 0, stream>>>(x, xb, Wqkv, wqkvt, Wo, wot);
  // K/V columns: fused KV+Ksum partials (no Kt/Vt materialization)
  gemm256<3><<<dim3(8, M_/256), 512, 0, stream>>>(xb, wqkvt, nullptr, nullptr, kvpp, kspp,
                                                  nullptr, M_, N1_, D_);
  // sum partials + W~T precompute (merged kvsum+kvw)
  kvw_kernel<<<64, 512, 0, stream>>>(kvpp, kspp, wot, wt, ksg);
  // Q columns: elu+1 with fused per-head normalizer -> Q~ in qbuf
  gemm256<4><<<dim3(4, M_/256), 512, 0, stream>>>(xb, wqkvt, nullptr, qbuf, nullptr, nullptr,
                                                  ksg, M_, N1_, D_);
  // out = Q~ @ W~_b (per-batch B via compile-time MODE=2), fp32 out
  gemm256<2><<<dim3(4, M_/256), 512, 0, stream>>>(qbuf, wt, out, nullptr, nullptr, nullptr,
                                                  nullptr, M_, D_, D_);
}